// Round 5
// baseline (1256.401 us; speedup 1.0000x reference)
//
#include <hip/hip_runtime.h>

#define DI __device__ __forceinline__

typedef __attribute__((ext_vector_type(8))) short short8;
typedef __attribute__((ext_vector_type(4))) float f32x4;

constexpr int THREADS = 512;           // 8 waves
constexpr int ROWS    = 16;            // batch rows per block
constexpr int NBLK    = 8192 / ROWS;   // 512 blocks -> 2 blocks/CU
constexpr int PITCH_H  = 272;          // h rows (K=128 bf16)
constexpr int PITCH_X  = 264;          // x rows
constexpr int PITCH_GI = 776;          // gi rows: 3 planes x 256B + 8 pad
constexpr int PITCH_A1 = 528;          // K=256 bf16 rows

// ---- LDS layout (bytes), total 54784 -> 2 blocks/CU with big margin ----
constexpr int O_PATCH = 0;        // 2560: 32 rows x 80B (2 steps x 16 rows)
constexpr int O_XALL  = 2560;     // 8448: 32 rows x 264B
constexpr int O_GI    = 11008;    // 24832: 32 rows x 776B (also conv-w scratch at init)
// decoder aliases of [0, 44544):
constexpr int O_FC2D  = 0;        // 33792: 64 x 528
constexpr int O_A1D   = 33792;    // 8448:  16 x 528
constexpr int O_A2D   = 42240;    // 2304:  16 x 144
constexpr int O_H     = 44544;    // 2 x 4352 hidden double buffer
constexpr int HBUF    = 4352;
constexpr int O_FC3W  = 53248;    // 1536: fc3 weights f32
constexpr int LDS_TOTAL = 54784;

// ---- d_ws element offsets (unsigned short / bf16) ----
constexpr int W_EWIH = 0;         // 384x128
constexpr int W_EWHH = 49152;
constexpr int W_DWIH = 98304;
constexpr int W_DWHH = 147456;
constexpr int W_FC1  = 196608;    // 256x128
constexpr int W_FC2  = 229376;    // 64x256
constexpr int W_END  = 245760;    // 491520 bytes

DI unsigned short f2bf(float f){
  union { float f; unsigned u; } v; v.f = f;
  return (unsigned short)((v.u + 0x7fffu + ((v.u >> 16) & 1u)) >> 16);
}
DI float bf2f(unsigned short u){
  union { unsigned u; float f; } v; v.u = ((unsigned)u) << 16;
  return v.f;
}
DI float sigm(float x){ return 1.f / (1.f + __expf(-x)); }
DI float tanh_(float x){
  float ax = fabsf(x);
  float e = __expf(-2.f * ax);
  float t = (1.f - e) / (1.f + e);
  return copysignf(t, x);
}
DI f32x4 mfma16(short8 a, short8 b, f32x4 c){
  return __builtin_amdgcn_mfma_f32_16x16x32_bf16(a, b, c, 0, 0, 0);
}

// ---------- prep: convert f32 weights -> bf16 in d_ws (runs every launch) ----------
__global__ void prep_weights(const float* __restrict__ ewih, const float* __restrict__ ewhh,
                             const float* __restrict__ dwih, const float* __restrict__ dwhh,
                             const float* __restrict__ f1,   const float* __restrict__ f2,
                             unsigned short* __restrict__ ws)
{
  const int gid = blockIdx.x * blockDim.x + threadIdx.x;
  const int stride = gridDim.x * blockDim.x;
  auto cvt = [&](const float* __restrict__ s, unsigned short* __restrict__ d, int n){
    for (int i = gid; i < (n >> 1); i += stride){
      float2 v = ((const float2*)s)[i];
      ((unsigned*)d)[i] = (unsigned)f2bf(v.x) | ((unsigned)f2bf(v.y) << 16);
    }
  };
  cvt(ewih, ws + W_EWIH, 49152);
  cvt(ewhh, ws + W_EWHH, 49152);
  cvt(dwih, ws + W_DWIH, 49152);
  cvt(dwhh, ws + W_DWHH, 49152);
  cvt(f1,   ws + W_FC1,  32768);
  cvt(f2,   ws + W_FC2,  16384);
}

// B-frag load from converted weights: row-major [row][128] bf16
DI short8 ldw(const unsigned short* __restrict__ base, int row, int kt, int quad){
  return *(const short8*)(base + row * 128 + kt * 32 + quad * 8);
}

__global__ void __launch_bounds__(THREADS, 4)
gru_fused(const float* __restrict__ past,
          const float* __restrict__ conv_w, const float* __restrict__ conv_b,
          const float* __restrict__ bn_gamma, const float* __restrict__ bn_beta,
          const float* __restrict__ bn_mean, const float* __restrict__ bn_var,
          const float* __restrict__ enc_bih, const float* __restrict__ enc_bhh,
          const float* __restrict__ dec_bih, const float* __restrict__ dec_bhh,
          const float* __restrict__ fc1_b, const float* __restrict__ fc2_b,
          const float* __restrict__ fc3_w, const float* __restrict__ fc3_b,
          const unsigned short* __restrict__ wsw,
          float* __restrict__ out)
{
  extern __shared__ char smem[];
  const int tid  = threadIdx.x;
  const int lane = tid & 63, w = tid >> 6;        // wave w owns gate-col slice w*16..
  const int l15  = lane & 15, quad = lane >> 4;
  const int b0   = blockIdx.x * ROWS;
  const int col  = w * 16 + l15;
  const float* pbase = past + (size_t)b0 * 768;

  // ---- encoder scalar constants ----
  const float br_e  = enc_bih[col]       + enc_bhh[col];
  const float bz_e  = enc_bih[128 + col] + enc_bhh[128 + col];
  const float bin_e = enc_bih[256 + col];
  const float bhn_e = enc_bhh[256 + col];
  const float cb_t  = conv_b[col];
  const float s_bn  = bn_gamma[0] * rsqrtf(bn_var[0] + 1e-5f);
  const float o_bn  = bn_beta[0] - bn_mean[0] * s_bn;

  // ---- recurrent weights -> registers (direct from d_ws, L2-hit) ----
  short8 wh[3][4];
  #pragma unroll
  for (int g = 0; g < 3; ++g)
    #pragma unroll
    for (int kt = 0; kt < 4; ++kt)
      wh[g][kt] = ldw(wsw + W_EWHH, g*128 + col, kt, quad);

  // ---- conv weights: build cwT[oc][k=c*3+kk] bf16 (80B rows) in GI scratch ----
  for (int i = tid; i < 2560; i += THREADS) ((unsigned*)(smem + O_GI))[i] = 0u;
  __syncthreads();
  for (int i = tid; i < 2304; i += THREADS){
    int oc = i / 18, kk = i - oc * 18;
    *(unsigned short*)(smem + O_GI + oc*80 + kk*2) = f2bf(conv_w[i]);
  }
  __syncthreads();
  const short8 cwf = *(const short8*)(smem + O_GI + col*80 + quad*16);

  // ---- zero h double buffer, load fc3 weights ----
  for (int i = tid; i < 2*HBUF/4; i += THREADS) ((unsigned*)(smem + O_H))[i] = 0u;
  for (int i = tid; i < 384; i += THREADS) ((float*)(smem + O_FC3W))[i] = fc3_w[i];
  __syncthreads();   // cwf reads done before GI reused for gi

  float hreg[4] = {0.f, 0.f, 0.f, 0.f};

  // ================= encoder: 64 chunks x 2 steps =================
  for (int chunk = 0; chunk < 64; ++chunk){
    const int t0 = chunk * 2;
    // ---- A1: im2col patch (2 steps x 16 rows x 18) from global (L2/L3-hot) ----
    for (int e = tid; e < 576; e += THREADS){
      int row = e / 18, r18 = e - row*18;
      int m16 = row & 15, tcs = row >> 4;
      int c = r18 / 3, kk = r18 - c*3;
      int tin = t0 + tcs - 1 + kk;
      float v = (tin >= 0 && tin < 128) ? pbase[(size_t)m16*768 + c*128 + tin] : 0.f;
      *(unsigned short*)(smem + O_PATCH + row*80 + r18*2) = f2bf(v);
    }
    __syncthreads();
    // ---- A2: conv (M=32 MFMA) + bias/relu/bn -> x_all ----
    #pragma unroll
    for (int mt = 0; mt < 2; ++mt){
      short8 pa = *(const short8*)(smem + O_PATCH + (mt*16 + l15)*80 + quad*16);
      f32x4 cc = (f32x4){0.f,0.f,0.f,0.f};
      cc = mfma16(pa, cwf, cc);
      #pragma unroll
      for (int r = 0; r < 4; ++r){
        int row = mt*16 + quad*4 + r;
        float vx = s_bn * fmaxf(cc[r] + cb_t, 0.f) + o_bn;
        *(unsigned short*)(smem + O_XALL + row*PITCH_X + col*2) = f2bf(vx);
      }
    }
    __syncthreads();
    // ---- A3: gi GEMM, wf B-frags straight from global (transient regs) ----
    #pragma unroll
    for (int g = 0; g < 3; ++g){
      short8 bf[4];
      #pragma unroll
      for (int kt = 0; kt < 4; ++kt) bf[kt] = ldw(wsw + W_EWIH, g*128 + col, kt, quad);
      const float bias = (g == 0) ? br_e : (g == 1) ? bz_e : bin_e;
      #pragma unroll
      for (int tc = 0; tc < 2; ++tc){
        short8 xa[4];
        #pragma unroll
        for (int kt = 0; kt < 4; ++kt)
          xa[kt] = *(const short8*)(smem + O_XALL + (tc*16 + l15)*PITCH_X + kt*64 + quad*16);
        f32x4 acc = (f32x4){0.f,0.f,0.f,0.f};
        #pragma unroll
        for (int kt = 0; kt < 4; ++kt) acc = mfma16(xa[kt], bf[kt], acc);
        #pragma unroll
        for (int r = 0; r < 4; ++r)
          *(unsigned short*)(smem + O_GI + (tc*16 + quad*4 + r)*PITCH_GI + g*256 + col*2) =
              f2bf(acc[r] + bias);
      }
    }
    __syncthreads();
    // ---- 2 recurrent steps, 1 barrier each ----
    #pragma unroll
    for (int tc = 0; tc < 2; ++tc){
      const int t = t0 + tc;
      const char* hr = smem + O_H + (t & 1) * HBUF;
      char*       hw = smem + O_H + ((t + 1) & 1) * HBUF;
      short8 ha[4];
      #pragma unroll
      for (int kt = 0; kt < 4; ++kt)
        ha[kt] = *(const short8*)(hr + l15*PITCH_H + kt*64 + quad*16);
      f32x4 ar, az, gin, an = (f32x4){0.f,0.f,0.f,0.f};
      #pragma unroll
      for (int r = 0; r < 4; ++r){
        const char* gb = smem + O_GI + (tc*16 + quad*4 + r)*PITCH_GI + col*2;
        ar[r]  = bf2f(*(const unsigned short*)gb);
        az[r]  = bf2f(*(const unsigned short*)(gb + 256));
        gin[r] = bf2f(*(const unsigned short*)(gb + 512));
      }
      #pragma unroll
      for (int kt = 0; kt < 4; ++kt){
        ar = mfma16(ha[kt], wh[0][kt], ar);
        az = mfma16(ha[kt], wh[1][kt], az);
        an = mfma16(ha[kt], wh[2][kt], an);
      }
      #pragma unroll
      for (int r = 0; r < 4; ++r){
        float rg = sigm(ar[r]);
        float zg = sigm(az[r]);
        float ng = tanh_(gin[r] + rg*(an[r] + bhn_e));
        hreg[r] = ng + zg*(hreg[r] - ng);
      }
      #pragma unroll
      for (int r = 0; r < 4; ++r)
        *(unsigned short*)(hw + (quad*4 + r)*PITCH_H + col*2) = f2bf(hreg[r]);
      __syncthreads();
    }
  }
  // h_enc in hbuf[0]

  // ================= decoder init =================
  // gi0 = h_enc @ dec_wih^T (B-frags direct from global, transient)
  f32x4 g0r, g0z, g0n;
  {
    short8 hea[4];
    #pragma unroll
    for (int kt = 0; kt < 4; ++kt)
      hea[kt] = *(const short8*)(smem + O_H + l15*PITCH_H + kt*64 + quad*16);
    #pragma unroll
    for (int g = 0; g < 3; ++g){
      short8 bf[4];
      #pragma unroll
      for (int kt = 0; kt < 4; ++kt) bf[kt] = ldw(wsw + W_DWIH, g*128 + col, kt, quad);
      f32x4 acc = (f32x4){0.f,0.f,0.f,0.f};
      #pragma unroll
      for (int kt = 0; kt < 4; ++kt) acc = mfma16(hea[kt], bf[kt], acc);
      if (g == 0) g0r = acc; else if (g == 1) g0z = acc; else g0n = acc;
    }
  }
  // decoder recurrent weights -> wh; fc1 frags -> regs
  #pragma unroll
  for (int g = 0; g < 3; ++g)
    #pragma unroll
    for (int kt = 0; kt < 4; ++kt)
      wh[g][kt] = ldw(wsw + W_DWHH, g*128 + col, kt, quad);
  short8 f1f[2][4];
  #pragma unroll
  for (int j = 0; j < 2; ++j)
    #pragma unroll
    for (int kt = 0; kt < 4; ++kt)
      f1f[j][kt] = ldw(wsw + W_FC1, w*32 + j*16 + l15, kt, quad);
  __syncthreads();   // all encoder-region LDS reads done before FC2D overwrite
  // fc2 -> LDS (repitch 512B rows -> 528B pitch)
  for (int i4 = tid; i4 < 4096; i4 += THREADS){
    int row = i4 >> 6, k8 = i4 & 63;
    *(uint2*)(smem + O_FC2D + row*PITCH_A1 + k8*8) =
        *(const uint2*)(wsw + W_FC2 + row*256 + k8*4);
  }
  // decoder scalar constants
  const float br_d  = dec_bih[col]       + dec_bhh[col];
  const float bz_d  = dec_bih[128 + col] + dec_bhh[128 + col];
  const float bin_d = dec_bih[256 + col];
  const float bhn_d = dec_bhh[256 + col];
  const float fb1a  = fc1_b[w * 32 + l15];
  const float fb1b  = fc1_b[w * 32 + 16 + l15];
  const float fb2   = (w < 4) ? fc2_b[w * 16 + l15] : 0.f;
  const int prow = tid / 6, pcol = tid - prow*6;
  float present = 0.f, fb3 = 0.f;
  if (tid < 96){
    present = pbase[(size_t)prow*768 + pcol*128 + 127];
    fb3 = fc3_b[pcol];
  }
  for (int i = tid; i < HBUF/4; i += THREADS) ((unsigned*)(smem + O_H + HBUF))[i] = 0u;
  #pragma unroll
  for (int r = 0; r < 4; ++r) hreg[r] = 0.f;
  __syncthreads();

  // ================= decoder: 30 steps, 3 barriers each =================
  for (int s = 0; s < 30; ++s){
    const char* hr = smem + O_H + (1 - (s & 1)) * HBUF;
    char*       hw = smem + O_H + (s & 1) * HBUF;
    f32x4 ar, az, gin, an = (f32x4){0.f,0.f,0.f,0.f};
    if (s == 0){
      #pragma unroll
      for (int r = 0; r < 4; ++r){
        ar[r] = g0r[r] + br_d; az[r] = g0z[r] + bz_d; gin[r] = g0n[r] + bin_d;
      }
    } else {
      #pragma unroll
      for (int r = 0; r < 4; ++r){ ar[r] = br_d; az[r] = bz_d; gin[r] = bin_d; }
    }
    {
      short8 ha[4];
      #pragma unroll
      for (int kt = 0; kt < 4; ++kt)
        ha[kt] = *(const short8*)(hr + l15*PITCH_H + kt*64 + quad*16);
      #pragma unroll
      for (int kt = 0; kt < 4; ++kt){
        ar = mfma16(ha[kt], wh[0][kt], ar);
        az = mfma16(ha[kt], wh[1][kt], az);
        an = mfma16(ha[kt], wh[2][kt], an);
      }
    }
    #pragma unroll
    for (int r = 0; r < 4; ++r){
      float rg = sigm(ar[r]);
      float zg = sigm(az[r]);
      float ng = tanh_(gin[r] + rg*(an[r] + bhn_d));
      hreg[r] = ng + zg*(hreg[r] - ng);
    }
    #pragma unroll
    for (int r = 0; r < 4; ++r)
      *(unsigned short*)(hw + (quad*4 + r)*PITCH_H + col*2) = f2bf(hreg[r]);
    __syncthreads();   // D1

    // fc1: (16x128)@(128x256) + relu -> a1
    {
      short8 hf[4];
      #pragma unroll
      for (int kt = 0; kt < 4; ++kt)
        hf[kt] = *(const short8*)(hw + l15*PITCH_H + kt*64 + quad*16);
      f32x4 a1a[2];
      a1a[0] = (f32x4){0.f,0.f,0.f,0.f}; a1a[1] = a1a[0];
      #pragma unroll
      for (int j = 0; j < 2; ++j)
        #pragma unroll
        for (int kt = 0; kt < 4; ++kt)
          a1a[j] = mfma16(hf[kt], f1f[j][kt], a1a[j]);
      #pragma unroll
      for (int j = 0; j < 2; ++j){
        float bb = j ? fb1b : fb1a;
        #pragma unroll
        for (int r = 0; r < 4; ++r)
          *(unsigned short*)(smem + O_A1D + (quad*4 + r)*PITCH_A1 +
                             (w*32 + j*16 + l15)*2) = f2bf(fmaxf(a1a[j][r] + bb, 0.f));
      }
    }
    __syncthreads();   // D2

    // fc2: (16x256)@(256x64) (waves 0-3)
    if (w < 4){
      f32x4 a2a = (f32x4){0.f,0.f,0.f,0.f};
      #pragma unroll
      for (int kt = 0; kt < 8; ++kt){
        short8 a = *(const short8*)(smem + O_A1D + l15*PITCH_A1 + kt*64 + quad*16);
        short8 b = *(const short8*)(smem + O_FC2D + (w*16 + l15)*PITCH_A1 + kt*64 + quad*16);
        a2a = mfma16(a, b, a2a);
      }
      #pragma unroll
      for (int r = 0; r < 4; ++r)
        *(unsigned short*)(smem + O_A2D + (quad*4 + r)*144 + (w*16 + l15)*2) =
            f2bf(a2a[r] + fb2);
    }
    __syncthreads();   // D3

    // fc3 (6x64, VALU) + present accumulate + store
    if (tid < 96){
      float o = fb3;
      const float* w3 = (const float*)(smem + O_FC3W) + pcol*64;
      #pragma unroll
      for (int kc = 0; kc < 8; ++kc){
        short8 av = *(const short8*)(smem + O_A2D + prow*144 + kc*16);
        #pragma unroll
        for (int j = 0; j < 8; ++j)
          o += bf2f((unsigned short)av[j]) * w3[kc*8 + j];
      }
      present += o;
      out[(size_t)(b0 + prow)*180 + pcol*30 + s] = present;   // (B, 6, 30)
    }
    // a2 reads protected by next step's D1/D2
  }
}

extern "C" void kernel_launch(void* const* d_in, const int* in_sizes, int n_in,
                              void* d_out, int out_size, void* d_ws, size_t ws_size,
                              hipStream_t stream) {
  (void)in_sizes; (void)n_in; (void)out_size; (void)ws_size;
  const float* past     = (const float*)d_in[0];
  const float* conv_w   = (const float*)d_in[1];
  const float* conv_b   = (const float*)d_in[2];
  const float* bn_gamma = (const float*)d_in[3];
  const float* bn_beta  = (const float*)d_in[4];
  const float* bn_mean  = (const float*)d_in[5];
  const float* bn_var   = (const float*)d_in[6];
  const float* enc_wih  = (const float*)d_in[7];
  const float* enc_whh  = (const float*)d_in[8];
  const float* enc_bih  = (const float*)d_in[9];
  const float* enc_bhh  = (const float*)d_in[10];
  const float* dec_wih  = (const float*)d_in[11];
  const float* dec_whh  = (const float*)d_in[12];
  const float* dec_bih  = (const float*)d_in[13];
  const float* dec_bhh  = (const float*)d_in[14];
  const float* fc1_w    = (const float*)d_in[15];
  const float* fc1_b    = (const float*)d_in[16];
  const float* fc2_w    = (const float*)d_in[17];
  const float* fc2_b    = (const float*)d_in[18];
  const float* fc3_w    = (const float*)d_in[19];
  const float* fc3_b    = (const float*)d_in[20];
  unsigned short* wsw   = (unsigned short*)d_ws;

  hipFuncSetAttribute((const void*)gru_fused,
                      hipFuncAttributeMaxDynamicSharedMemorySize, LDS_TOTAL);

  prep_weights<<<256, 256, 0, stream>>>(enc_wih, enc_whh, dec_wih, dec_whh,
                                        fc1_w, fc2_w, wsw);

  gru_fused<<<NBLK, THREADS, LDS_TOTAL, stream>>>(
      past, conv_w, conv_b, bn_gamma, bn_beta, bn_mean, bn_var,
      enc_bih, enc_bhh, dec_bih, dec_bhh,
      fc1_b, fc2_b, fc3_w, fc3_b, wsw,
      (float*)d_out);
}

// Round 6
// 1110.435 us; speedup vs baseline: 1.1314x; 1.1314x over previous
//
#include <hip/hip_runtime.h>

#define DI __device__ __forceinline__

typedef __attribute__((ext_vector_type(8))) short short8;
typedef __attribute__((ext_vector_type(4))) float f32x4;

constexpr int THREADS = 512;           // 8 waves
constexpr int ROWS    = 16;            // batch rows per block
constexpr int NBLK    = 8192 / ROWS;   // 512 blocks -> 2 blocks/CU
constexpr int PITCH_H  = 272;          // h rows (K=128 bf16)
constexpr int PITCH_X  = 264;          // x rows
constexpr int PITCH_GI = 776;          // gi rows: 3 planes x 256B + 8 pad
constexpr int PITCH_A1 = 528;          // K=256 bf16 rows

// ---- LDS layout (bytes), total 54784 -> 2 blocks/CU ----
constexpr int O_PATCH = 0;        // 2560: 32 rows x 80B (2 steps x 16 rows)
constexpr int O_XALL  = 2560;     // 8448: 32 rows x 264B
constexpr int O_GI    = 11008;    // 24832: 32 rows x 776B (also conv-w scratch at init)
// decoder aliases of [0, 44544):
constexpr int O_FC2D  = 0;        // 33792: 64 x 528
constexpr int O_A1D   = 33792;    // 8448:  16 x 528
constexpr int O_A2D   = 42240;    // 2304:  16 x 144
constexpr int O_H     = 44544;    // 2 x 4352 hidden double buffer
constexpr int HBUF    = 4352;
constexpr int O_FC3W  = 53248;    // 1536: fc3 weights f32
constexpr int LDS_TOTAL = 54784;

// ---- d_ws element offsets (unsigned short / bf16) ----
constexpr int W_EWIH = 0;         // 384x128
constexpr int W_EWHH = 49152;
constexpr int W_DWIH = 98304;
constexpr int W_DWHH = 147456;
constexpr int W_FC1  = 196608;    // 256x128
constexpr int W_FC2  = 229376;    // 64x256

DI unsigned short f2bf(float f){
  union { float f; unsigned u; } v; v.f = f;
  return (unsigned short)((v.u + 0x7fffu + ((v.u >> 16) & 1u)) >> 16);
}
DI float bf2f(unsigned short u){
  union { unsigned u; float f; } v; v.u = ((unsigned)u) << 16;
  return v.f;
}
DI float sigm(float x){ return 1.f / (1.f + __expf(-x)); }
DI float tanh_(float x){
  float ax = fabsf(x);
  float e = __expf(-2.f * ax);
  float t = (1.f - e) / (1.f + e);
  return copysignf(t, x);
}
DI f32x4 mfma16(short8 a, short8 b, f32x4 c){
  return __builtin_amdgcn_mfma_f32_16x16x32_bf16(a, b, c, 0, 0, 0);
}

// ---------- prep: convert f32 weights -> bf16 in d_ws (runs every launch) ----------
__global__ void prep_weights(const float* __restrict__ ewih, const float* __restrict__ ewhh,
                             const float* __restrict__ dwih, const float* __restrict__ dwhh,
                             const float* __restrict__ f1,   const float* __restrict__ f2,
                             unsigned short* __restrict__ ws)
{
  const int gid = blockIdx.x * blockDim.x + threadIdx.x;
  const int stride = gridDim.x * blockDim.x;
  auto cvt = [&](const float* __restrict__ s, unsigned short* __restrict__ d, int n){
    for (int i = gid; i < (n >> 1); i += stride){
      float2 v = ((const float2*)s)[i];
      ((unsigned*)d)[i] = (unsigned)f2bf(v.x) | ((unsigned)f2bf(v.y) << 16);
    }
  };
  cvt(ewih, ws + W_EWIH, 49152);
  cvt(ewhh, ws + W_EWHH, 49152);
  cvt(dwih, ws + W_DWIH, 49152);
  cvt(dwhh, ws + W_DWHH, 49152);
  cvt(f1,   ws + W_FC1,  32768);
  cvt(f2,   ws + W_FC2,  16384);
}

// B-frag load from converted weights: row-major [row][128] bf16
DI short8 ldw(const unsigned short* __restrict__ base, int row, int kt, int quad){
  return *(const short8*)(base + row * 128 + kt * 32 + quad * 8);
}

// NOTE: 2nd __launch_bounds__ arg behaves as min BLOCKS/CU on this compiler
// (evidence: (512,4) -> VGPR cap 64 = 32 waves/CU; (512,2) -> cap 128 = 16 waves/CU).
// We need the 128-VGPR class: 2 blocks/CU x 8 waves.
__global__ void __launch_bounds__(THREADS, 2)
gru_fused(const float* __restrict__ past,
          const float* __restrict__ conv_w, const float* __restrict__ conv_b,
          const float* __restrict__ bn_gamma, const float* __restrict__ bn_beta,
          const float* __restrict__ bn_mean, const float* __restrict__ bn_var,
          const float* __restrict__ enc_bih, const float* __restrict__ enc_bhh,
          const float* __restrict__ dec_bih, const float* __restrict__ dec_bhh,
          const float* __restrict__ fc1_b, const float* __restrict__ fc2_b,
          const float* __restrict__ fc3_w, const float* __restrict__ fc3_b,
          const unsigned short* __restrict__ wsw,
          float* __restrict__ out)
{
  extern __shared__ char smem[];
  const int tid  = threadIdx.x;
  const int lane = tid & 63, w = tid >> 6;        // wave w owns gate-col slice w*16..
  const int l15  = lane & 15, quad = lane >> 4;
  const int b0   = blockIdx.x * ROWS;
  const int col  = w * 16 + l15;
  const float* pbase = past + (size_t)b0 * 768;

  // ---- encoder scalar constants ----
  const float br_e  = enc_bih[col]       + enc_bhh[col];
  const float bz_e  = enc_bih[128 + col] + enc_bhh[128 + col];
  const float bin_e = enc_bih[256 + col];
  const float bhn_e = enc_bhh[256 + col];
  const float cb_t  = conv_b[col];
  const float s_bn  = bn_gamma[0] * rsqrtf(bn_var[0] + 1e-5f);
  const float o_bn  = bn_beta[0] - bn_mean[0] * s_bn;

  // ---- recurrent weights -> registers (direct from d_ws, L2-hit) ----
  short8 wh[3][4];
  #pragma unroll
  for (int g = 0; g < 3; ++g)
    #pragma unroll
    for (int kt = 0; kt < 4; ++kt)
      wh[g][kt] = ldw(wsw + W_EWHH, g*128 + col, kt, quad);

  // ---- conv weights: build cwT[oc][k=c*3+kk] bf16 (80B rows) in GI scratch ----
  for (int i = tid; i < 2560; i += THREADS) ((unsigned*)(smem + O_GI))[i] = 0u;
  __syncthreads();
  for (int i = tid; i < 2304; i += THREADS){
    int oc = i / 18, kk = i - oc * 18;
    *(unsigned short*)(smem + O_GI + oc*80 + kk*2) = f2bf(conv_w[i]);
  }
  __syncthreads();
  const short8 cwf = *(const short8*)(smem + O_GI + col*80 + quad*16);

  // ---- zero h double buffer, load fc3 weights ----
  for (int i = tid; i < 2*HBUF/4; i += THREADS) ((unsigned*)(smem + O_H))[i] = 0u;
  for (int i = tid; i < 384; i += THREADS) ((float*)(smem + O_FC3W))[i] = fc3_w[i];
  __syncthreads();   // cwf reads done before GI reused for gi

  float hreg[4] = {0.f, 0.f, 0.f, 0.f};

  // ================= encoder: 64 chunks x 2 steps =================
  for (int chunk = 0; chunk < 64; ++chunk){
    const int t0 = chunk * 2;
    // ---- A1: im2col patch (2 steps x 16 rows x 18) from global (L2/L3-hot) ----
    for (int e = tid; e < 576; e += THREADS){
      int row = e / 18, r18 = e - row*18;
      int m16 = row & 15, tcs = row >> 4;
      int c = r18 / 3, kk = r18 - c*3;
      int tin = t0 + tcs - 1 + kk;
      float v = (tin >= 0 && tin < 128) ? pbase[(size_t)m16*768 + c*128 + tin] : 0.f;
      *(unsigned short*)(smem + O_PATCH + row*80 + r18*2) = f2bf(v);
    }
    __syncthreads();
    // ---- A2: conv (M=32 MFMA) + bias/relu/bn -> x_all ----
    #pragma unroll
    for (int mt = 0; mt < 2; ++mt){
      short8 pa = *(const short8*)(smem + O_PATCH + (mt*16 + l15)*80 + quad*16);
      f32x4 cc = (f32x4){0.f,0.f,0.f,0.f};
      cc = mfma16(pa, cwf, cc);
      #pragma unroll
      for (int r = 0; r < 4; ++r){
        int row = mt*16 + quad*4 + r;
        float vx = s_bn * fmaxf(cc[r] + cb_t, 0.f) + o_bn;
        *(unsigned short*)(smem + O_XALL + row*PITCH_X + col*2) = f2bf(vx);
      }
    }
    __syncthreads();
    // ---- A3: gi GEMM, wf B-frags straight from global (transient regs) ----
    #pragma unroll
    for (int g = 0; g < 3; ++g){
      short8 bf[4];
      #pragma unroll
      for (int kt = 0; kt < 4; ++kt) bf[kt] = ldw(wsw + W_EWIH, g*128 + col, kt, quad);
      const float bias = (g == 0) ? br_e : (g == 1) ? bz_e : bin_e;
      #pragma unroll
      for (int tc = 0; tc < 2; ++tc){
        short8 xa[4];
        #pragma unroll
        for (int kt = 0; kt < 4; ++kt)
          xa[kt] = *(const short8*)(smem + O_XALL + (tc*16 + l15)*PITCH_X + kt*64 + quad*16);
        f32x4 acc = (f32x4){0.f,0.f,0.f,0.f};
        #pragma unroll
        for (int kt = 0; kt < 4; ++kt) acc = mfma16(xa[kt], bf[kt], acc);
        #pragma unroll
        for (int r = 0; r < 4; ++r)
          *(unsigned short*)(smem + O_GI + (tc*16 + quad*4 + r)*PITCH_GI + g*256 + col*2) =
              f2bf(acc[r] + bias);
      }
    }
    __syncthreads();
    // ---- 2 recurrent steps, 1 barrier each ----
    #pragma unroll
    for (int tc = 0; tc < 2; ++tc){
      const int t = t0 + tc;
      const char* hr = smem + O_H + (t & 1) * HBUF;
      char*       hw = smem + O_H + ((t + 1) & 1) * HBUF;
      short8 ha[4];
      #pragma unroll
      for (int kt = 0; kt < 4; ++kt)
        ha[kt] = *(const short8*)(hr + l15*PITCH_H + kt*64 + quad*16);
      f32x4 ar, az, gin, an = (f32x4){0.f,0.f,0.f,0.f};
      #pragma unroll
      for (int r = 0; r < 4; ++r){
        const char* gb = smem + O_GI + (tc*16 + quad*4 + r)*PITCH_GI + col*2;
        ar[r]  = bf2f(*(const unsigned short*)gb);
        az[r]  = bf2f(*(const unsigned short*)(gb + 256));
        gin[r] = bf2f(*(const unsigned short*)(gb + 512));
      }
      #pragma unroll
      for (int kt = 0; kt < 4; ++kt){
        ar = mfma16(ha[kt], wh[0][kt], ar);
        az = mfma16(ha[kt], wh[1][kt], az);
        an = mfma16(ha[kt], wh[2][kt], an);
      }
      #pragma unroll
      for (int r = 0; r < 4; ++r){
        float rg = sigm(ar[r]);
        float zg = sigm(az[r]);
        float ng = tanh_(gin[r] + rg*(an[r] + bhn_e));
        hreg[r] = ng + zg*(hreg[r] - ng);
      }
      #pragma unroll
      for (int r = 0; r < 4; ++r)
        *(unsigned short*)(hw + (quad*4 + r)*PITCH_H + col*2) = f2bf(hreg[r]);
      __syncthreads();
    }
  }
  // h_enc in hbuf[0]

  // ================= decoder init =================
  // gi0 = h_enc @ dec_wih^T (B-frags direct from global, transient)
  f32x4 g0r, g0z, g0n;
  {
    short8 hea[4];
    #pragma unroll
    for (int kt = 0; kt < 4; ++kt)
      hea[kt] = *(const short8*)(smem + O_H + l15*PITCH_H + kt*64 + quad*16);
    #pragma unroll
    for (int g = 0; g < 3; ++g){
      short8 bf[4];
      #pragma unroll
      for (int kt = 0; kt < 4; ++kt) bf[kt] = ldw(wsw + W_DWIH, g*128 + col, kt, quad);
      f32x4 acc = (f32x4){0.f,0.f,0.f,0.f};
      #pragma unroll
      for (int kt = 0; kt < 4; ++kt) acc = mfma16(hea[kt], bf[kt], acc);
      if (g == 0) g0r = acc; else if (g == 1) g0z = acc; else g0n = acc;
    }
  }
  // decoder recurrent weights -> wh; fc1 frags -> regs
  #pragma unroll
  for (int g = 0; g < 3; ++g)
    #pragma unroll
    for (int kt = 0; kt < 4; ++kt)
      wh[g][kt] = ldw(wsw + W_DWHH, g*128 + col, kt, quad);
  short8 f1f[2][4];
  #pragma unroll
  for (int j = 0; j < 2; ++j)
    #pragma unroll
    for (int kt = 0; kt < 4; ++kt)
      f1f[j][kt] = ldw(wsw + W_FC1, w*32 + j*16 + l15, kt, quad);
  __syncthreads();   // all encoder-region LDS reads done before FC2D overwrite
  // fc2 -> LDS (repitch 512B rows -> 528B pitch)
  for (int i4 = tid; i4 < 4096; i4 += THREADS){
    int row = i4 >> 6, k8 = i4 & 63;
    *(uint2*)(smem + O_FC2D + row*PITCH_A1 + k8*8) =
        *(const uint2*)(wsw + W_FC2 + row*256 + k8*4);
  }
  // decoder scalar constants
  const float br_d  = dec_bih[col]       + dec_bhh[col];
  const float bz_d  = dec_bih[128 + col] + dec_bhh[128 + col];
  const float bin_d = dec_bih[256 + col];
  const float bhn_d = dec_bhh[256 + col];
  const float fb1a  = fc1_b[w * 32 + l15];
  const float fb1b  = fc1_b[w * 32 + 16 + l15];
  const float fb2   = (w < 4) ? fc2_b[w * 16 + l15] : 0.f;
  const int prow = tid / 6, pcol = tid - prow*6;
  float present = 0.f, fb3 = 0.f;
  if (tid < 96){
    present = pbase[(size_t)prow*768 + pcol*128 + 127];
    fb3 = fc3_b[pcol];
  }
  for (int i = tid; i < HBUF/4; i += THREADS) ((unsigned*)(smem + O_H + HBUF))[i] = 0u;
  #pragma unroll
  for (int r = 0; r < 4; ++r) hreg[r] = 0.f;
  __syncthreads();

  // ================= decoder: 30 steps, 3 barriers each =================
  for (int s = 0; s < 30; ++s){
    const char* hr = smem + O_H + (1 - (s & 1)) * HBUF;
    char*       hw = smem + O_H + (s & 1) * HBUF;
    f32x4 ar, az, gin, an = (f32x4){0.f,0.f,0.f,0.f};
    if (s == 0){
      #pragma unroll
      for (int r = 0; r < 4; ++r){
        ar[r] = g0r[r] + br_d; az[r] = g0z[r] + bz_d; gin[r] = g0n[r] + bin_d;
      }
    } else {
      #pragma unroll
      for (int r = 0; r < 4; ++r){ ar[r] = br_d; az[r] = bz_d; gin[r] = bin_d; }
    }
    {
      short8 ha[4];
      #pragma unroll
      for (int kt = 0; kt < 4; ++kt)
        ha[kt] = *(const short8*)(hr + l15*PITCH_H + kt*64 + quad*16);
      #pragma unroll
      for (int kt = 0; kt < 4; ++kt){
        ar = mfma16(ha[kt], wh[0][kt], ar);
        az = mfma16(ha[kt], wh[1][kt], az);
        an = mfma16(ha[kt], wh[2][kt], an);
      }
    }
    #pragma unroll
    for (int r = 0; r < 4; ++r){
      float rg = sigm(ar[r]);
      float zg = sigm(az[r]);
      float ng = tanh_(gin[r] + rg*(an[r] + bhn_d));
      hreg[r] = ng + zg*(hreg[r] - ng);
    }
    #pragma unroll
    for (int r = 0; r < 4; ++r)
      *(unsigned short*)(hw + (quad*4 + r)*PITCH_H + col*2) = f2bf(hreg[r]);
    __syncthreads();   // D1

    // fc1: (16x128)@(128x256) + relu -> a1
    {
      short8 hf[4];
      #pragma unroll
      for (int kt = 0; kt < 4; ++kt)
        hf[kt] = *(const short8*)(hw + l15*PITCH_H + kt*64 + quad*16);
      f32x4 a1a[2];
      a1a[0] = (f32x4){0.f,0.f,0.f,0.f}; a1a[1] = a1a[0];
      #pragma unroll
      for (int j = 0; j < 2; ++j)
        #pragma unroll
        for (int kt = 0; kt < 4; ++kt)
          a1a[j] = mfma16(hf[kt], f1f[j][kt], a1a[j]);
      #pragma unroll
      for (int j = 0; j < 2; ++j){
        float bb = j ? fb1b : fb1a;
        #pragma unroll
        for (int r = 0; r < 4; ++r)
          *(unsigned short*)(smem + O_A1D + (quad*4 + r)*PITCH_A1 +
                             (w*32 + j*16 + l15)*2) = f2bf(fmaxf(a1a[j][r] + bb, 0.f));
      }
    }
    __syncthreads();   // D2

    // fc2: (16x256)@(256x64) (waves 0-3)
    if (w < 4){
      f32x4 a2a = (f32x4){0.f,0.f,0.f,0.f};
      #pragma unroll
      for (int kt = 0; kt < 8; ++kt){
        short8 a = *(const short8*)(smem + O_A1D + l15*PITCH_A1 + kt*64 + quad*16);
        short8 b = *(const short8*)(smem + O_FC2D + (w*16 + l15)*PITCH_A1 + kt*64 + quad*16);
        a2a = mfma16(a, b, a2a);
      }
      #pragma unroll
      for (int r = 0; r < 4; ++r)
        *(unsigned short*)(smem + O_A2D + (quad*4 + r)*144 + (w*16 + l15)*2) =
            f2bf(a2a[r] + fb2);
    }
    __syncthreads();   // D3

    // fc3 (6x64, VALU) + present accumulate + store
    if (tid < 96){
      float o = fb3;
      const float* w3 = (const float*)(smem + O_FC3W) + pcol*64;
      #pragma unroll
      for (int kc = 0; kc < 8; ++kc){
        short8 av = *(const short8*)(smem + O_A2D + prow*144 + kc*16);
        #pragma unroll
        for (int j = 0; j < 8; ++j)
          o += bf2f((unsigned short)av[j]) * w3[kc*8 + j];
      }
      present += o;
      out[(size_t)(b0 + prow)*180 + pcol*30 + s] = present;   // (B, 6, 30)
    }
    // a2 reads protected by next step's D1/D2
  }
}

extern "C" void kernel_launch(void* const* d_in, const int* in_sizes, int n_in,
                              void* d_out, int out_size, void* d_ws, size_t ws_size,
                              hipStream_t stream) {
  (void)in_sizes; (void)n_in; (void)out_size; (void)ws_size;
  const float* past     = (const float*)d_in[0];
  const float* conv_w   = (const float*)d_in[1];
  const float* conv_b   = (const float*)d_in[2];
  const float* bn_gamma = (const float*)d_in[3];
  const float* bn_beta  = (const float*)d_in[4];
  const float* bn_mean  = (const float*)d_in[5];
  const float* bn_var   = (const float*)d_in[6];
  const float* enc_wih  = (const float*)d_in[7];
  const float* enc_whh  = (const float*)d_in[8];
  const float* enc_bih  = (const float*)d_in[9];
  const float* enc_bhh  = (const float*)d_in[10];
  const float* dec_wih  = (const float*)d_in[11];
  const float* dec_whh  = (const float*)d_in[12];
  const float* dec_bih  = (const float*)d_in[13];
  const float* dec_bhh  = (const float*)d_in[14];
  const float* fc1_w    = (const float*)d_in[15];
  const float* fc1_b    = (const float*)d_in[16];
  const float* fc2_w    = (const float*)d_in[17];
  const float* fc2_b    = (const float*)d_in[18];
  const float* fc3_w    = (const float*)d_in[19];
  const float* fc3_b    = (const float*)d_in[20];
  unsigned short* wsw   = (unsigned short*)d_ws;

  hipFuncSetAttribute((const void*)gru_fused,
                      hipFuncAttributeMaxDynamicSharedMemorySize, LDS_TOTAL);

  prep_weights<<<256, 256, 0, stream>>>(enc_wih, enc_whh, dec_wih, dec_whh,
                                        fc1_w, fc2_w, wsw);

  gru_fused<<<NBLK, THREADS, LDS_TOTAL, stream>>>(
      past, conv_w, conv_b, bn_gamma, bn_beta, bn_mean, bn_var,
      enc_bih, enc_bhh, dec_bih, dec_bhh,
      fc1_b, fc2_b, fc3_w, fc3_b, wsw,
      (float*)d_out);
}

// Round 7
// 1020.510 us; speedup vs baseline: 1.2311x; 1.0881x over previous
//
#include <hip/hip_runtime.h>

#define DI __device__ __forceinline__

typedef __attribute__((ext_vector_type(8))) short short8;
typedef __attribute__((ext_vector_type(4))) float f32x4;

constexpr int THREADS = 1024;          // 16 waves -> one block fills a CU (4 waves/SIMD)
constexpr int ROWS    = 32;            // batch rows per block
constexpr int NBLK    = 8192 / ROWS;   // 256 blocks = 1 per CU
constexpr int PITCH_H  = 272;          // h rows (K=128 bf16), b128-read conflict-free
constexpr int PITCH_X  = 264;          // x rows, conflict-free
constexpr int PITCH_A1 = 528;          // K=256 bf16 rows

// ---- LDS layout (bytes) ----
constexpr int O_PATCH = 0;        // 10240: 128 rows x 80B (4 steps x 32 rows); conv-w scratch at init
constexpr int O_XALL  = 10240;    // 33792: 128 rows x 264B
constexpr int O_H     = 44032;    // 2 x 8704 hidden double buffer
constexpr int HBUF    = 8704;
constexpr int O_FC3W  = 61440;    // 1536: fc3 weights f32
constexpr int O_A1D   = 62976;    // 16896: a1 (32 x 528)  [decoder]
constexpr int LDS_TOTAL = 79872;
// decoder aliases of [0, 44032):
constexpr int O_FC2D  = 0;        // 33792: 64 x 528
constexpr int O_A2D   = 33792;    // 4608:  32 x 144

// ---- d_ws element offsets (bf16) ----
constexpr int W_EWIH = 0;         // 384x128
constexpr int W_EWHH = 49152;
constexpr int W_DWIH = 98304;
constexpr int W_DWHH = 147456;
constexpr int W_FC1  = 196608;    // 256x128
constexpr int W_FC2  = 229376;    // 64x256

DI unsigned short f2bf(float f){
  union { float f; unsigned u; } v; v.f = f;
  return (unsigned short)((v.u + 0x7fffu + ((v.u >> 16) & 1u)) >> 16);
}
DI float bf2f(unsigned short u){
  union { unsigned u; float f; } v; v.u = ((unsigned)u) << 16;
  return v.f;
}
DI float u2f_lo(unsigned u){ union { unsigned u; float f; } v; v.u = u << 16;        return v.f; }
DI float u2f_hi(unsigned u){ union { unsigned u; float f; } v; v.u = u & 0xffff0000u; return v.f; }
DI float sigm(float x){ return 1.f / (1.f + __expf(-x)); }
DI float tanh_(float x){
  float ax = fabsf(x);
  float e = __expf(-2.f * ax);
  float t = (1.f - e) / (1.f + e);
  return copysignf(t, x);
}
DI f32x4 mfma16(short8 a, short8 b, f32x4 c){
  return __builtin_amdgcn_mfma_f32_16x16x32_bf16(a, b, c, 0, 0, 0);
}
DI uint2 pack4(f32x4 v){
  return make_uint2((unsigned)f2bf(v[0]) | ((unsigned)f2bf(v[1]) << 16),
                    (unsigned)f2bf(v[2]) | ((unsigned)f2bf(v[3]) << 16));
}

// ---------- prep: convert f32 weights -> bf16 in d_ws ----------
__global__ void prep_weights(const float* __restrict__ ewih, const float* __restrict__ ewhh,
                             const float* __restrict__ dwih, const float* __restrict__ dwhh,
                             const float* __restrict__ f1,   const float* __restrict__ f2,
                             unsigned short* __restrict__ ws)
{
  const int gid = blockIdx.x * blockDim.x + threadIdx.x;
  const int stride = gridDim.x * blockDim.x;
  auto cvt = [&](const float* __restrict__ s, unsigned short* __restrict__ d, int n){
    for (int i = gid; i < (n >> 1); i += stride){
      float2 v = ((const float2*)s)[i];
      ((unsigned*)d)[i] = (unsigned)f2bf(v.x) | ((unsigned)f2bf(v.y) << 16);
    }
  };
  cvt(ewih, ws + W_EWIH, 49152);
  cvt(ewhh, ws + W_EWHH, 49152);
  cvt(dwih, ws + W_DWIH, 49152);
  cvt(dwhh, ws + W_DWHH, 49152);
  cvt(f1,   ws + W_FC1,  32768);
  cvt(f2,   ws + W_FC2,  16384);
}

// B-frag load from converted weights: row-major [row][128] bf16
DI short8 ldw(const unsigned short* __restrict__ base, int row, int kt, int quad){
  return *(const short8*)(base + row * 128 + kt * 32 + quad * 8);
}

// Single-arg launch bounds: 1024-thread block = 16 waves = 4 waves/SIMD, which
// structurally forces total (VGPR+AGPR) <= 128/wave AND guarantees 16 resident
// waves/CU -- the occupancy the (512,N) 2nd-arg experiments failed to deliver.
__global__ void __launch_bounds__(THREADS)
gru_fused(const float* __restrict__ past,
          const float* __restrict__ conv_w, const float* __restrict__ conv_b,
          const float* __restrict__ bn_gamma, const float* __restrict__ bn_beta,
          const float* __restrict__ bn_mean, const float* __restrict__ bn_var,
          const float* __restrict__ enc_bih, const float* __restrict__ enc_bhh,
          const float* __restrict__ dec_bih, const float* __restrict__ dec_bhh,
          const float* __restrict__ fc1_b, const float* __restrict__ fc2_b,
          const float* __restrict__ fc3_w, const float* __restrict__ fc3_b,
          const unsigned short* __restrict__ wsw,
          float* __restrict__ out)
{
  extern __shared__ char smem[];
  const int tid  = threadIdx.x;
  const int lane = tid & 63, wv = tid >> 6;       // 16 waves
  const int mt   = wv >> 3, cs = wv & 7;          // m-tile (0/1), col-slice (0..7)
  const int l15  = lane & 15, quad = lane >> 4;
  const int b0   = blockIdx.x * ROWS;
  const int col  = cs * 16 + l15;                 // this thread's gate/h column
  const float* pbase = past + (size_t)b0 * 768;

  // ---- encoder scalar constants ----
  const float br_e  = enc_bih[col]       + enc_bhh[col];
  const float bz_e  = enc_bih[128 + col] + enc_bhh[128 + col];
  const float bin_e = enc_bih[256 + col];
  const float bhn_e = enc_bhh[256 + col];
  const float cb_t  = conv_b[col];
  const float s_bn  = bn_gamma[0] * rsqrtf(bn_var[0] + 1e-5f);
  const float o_bn  = bn_beta[0] - bn_mean[0] * s_bn;

  // ---- recurrent weights -> registers (from d_ws, one-time) ----
  short8 wh[3][4];
  #pragma unroll
  for (int g = 0; g < 3; ++g)
    #pragma unroll
    for (int kt = 0; kt < 4; ++kt)
      wh[g][kt] = ldw(wsw + W_EWHH, g*128 + col, kt, quad);

  // ---- conv weights: cwT[oc][k=c*3+kk] bf16 (80B rows) in PATCH scratch ----
  for (int i = tid; i < 2560; i += THREADS) ((unsigned*)(smem + O_PATCH))[i] = 0u;
  __syncthreads();
  for (int i = tid; i < 2304; i += THREADS){
    int oc = i / 18, kk = i - oc * 18;
    *(unsigned short*)(smem + O_PATCH + oc*80 + kk*2) = f2bf(conv_w[i]);
  }
  __syncthreads();
  const short8 cwf = *(const short8*)(smem + O_PATCH + col*80 + quad*16);

  // ---- zero h double buffer, fc3 weights ----
  for (int i = tid; i < 2*HBUF/4; i += THREADS) ((unsigned*)(smem + O_H))[i] = 0u;
  for (int i = tid; i < 384; i += THREADS) ((float*)(smem + O_FC3W))[i] = fc3_w[i];
  __syncthreads();   // cwf read done before PATCH reused

  float hreg[4] = {0.f, 0.f, 0.f, 0.f};
  uint2 gi_pk[4][3];                    // packed-bf16 gi (bias folded): [tc][gate]

  // ================= encoder: 32 chunks x 4 steps =================
  for (int chunk = 0; chunk < 32; ++chunk){
    const int t0 = chunk * 4;
    // ---- A1: im2col patch, 4 steps x 32 rows x 18, from global (L2-hot) ----
    for (int e = tid; e < 2304; e += THREADS){
      int tc = e / 576, rem = e - tc*576;
      int m = rem / 18, r18 = rem - m*18;
      int c = r18 / 3, kk = r18 - c*3;
      int tin = t0 + tc - 1 + kk;
      float v = (tin >= 0 && tin < 128) ? pbase[(size_t)m*768 + c*128 + tin] : 0.f;
      *(unsigned short*)(smem + O_PATCH + (tc*32 + m)*80 + r18*2) = f2bf(v);
    }
    __syncthreads();
    // ---- A2: conv as M=128 GEMM (4 row-tiles per wave) + bias/relu/bn ----
    #pragma unroll
    for (int i = 0; i < 4; ++i){
      const int rt = mt*4 + i;          // row-tile 0..7
      short8 pa = *(const short8*)(smem + O_PATCH + (rt*16 + l15)*80 + quad*16);
      f32x4 cc = (f32x4){0.f,0.f,0.f,0.f};
      cc = mfma16(pa, cwf, cc);
      #pragma unroll
      for (int r = 0; r < 4; ++r){
        int row = rt*16 + quad*4 + r;
        float vx = s_bn * fmaxf(cc[r] + cb_t, 0.f) + o_bn;
        *(unsigned short*)(smem + O_XALL + row*PITCH_X + col*2) = f2bf(vx);
      }
    }
    __syncthreads();
    // ---- A3: gi GEMM for 4 steps; wf streamed once per gate per chunk ----
    #pragma unroll
    for (int g = 0; g < 3; ++g){
      short8 bfr[4];
      #pragma unroll
      for (int kt = 0; kt < 4; ++kt) bfr[kt] = ldw(wsw + W_EWIH, g*128 + col, kt, quad);
      const float bias = (g == 0) ? br_e : (g == 1) ? bz_e : bin_e;
      #pragma unroll
      for (int tc = 0; tc < 4; ++tc){
        f32x4 acc = (f32x4){0.f,0.f,0.f,0.f};
        #pragma unroll
        for (int kt = 0; kt < 4; ++kt){
          short8 xa = *(const short8*)(smem + O_XALL +
                        (tc*32 + mt*16 + l15)*PITCH_X + kt*64 + quad*16);
          acc = mfma16(xa, bfr[kt], acc);
        }
        #pragma unroll
        for (int r = 0; r < 4; ++r) acc[r] += bias;
        gi_pk[tc][g] = pack4(acc);
      }
    }
    // x_all reads complete before next chunk's A2 (protected by step barriers + A1 barrier)

    // ---- 4 recurrent steps, 1 barrier each ----
    #pragma unroll
    for (int tc = 0; tc < 4; ++tc){
      const int t = t0 + tc;
      const char* hr = smem + O_H + (t & 1) * HBUF;
      char*       hw = smem + O_H + ((t + 1) & 1) * HBUF;
      short8 ha[4];
      #pragma unroll
      for (int kt = 0; kt < 4; ++kt)
        ha[kt] = *(const short8*)(hr + (mt*16 + l15)*PITCH_H + kt*64 + quad*16);
      f32x4 ar, az, gin, an = (f32x4){0.f,0.f,0.f,0.f};
      ar[0]=u2f_lo(gi_pk[tc][0].x); ar[1]=u2f_hi(gi_pk[tc][0].x);
      ar[2]=u2f_lo(gi_pk[tc][0].y); ar[3]=u2f_hi(gi_pk[tc][0].y);
      az[0]=u2f_lo(gi_pk[tc][1].x); az[1]=u2f_hi(gi_pk[tc][1].x);
      az[2]=u2f_lo(gi_pk[tc][1].y); az[3]=u2f_hi(gi_pk[tc][1].y);
      gin[0]=u2f_lo(gi_pk[tc][2].x); gin[1]=u2f_hi(gi_pk[tc][2].x);
      gin[2]=u2f_lo(gi_pk[tc][2].y); gin[3]=u2f_hi(gi_pk[tc][2].y);
      #pragma unroll
      for (int kt = 0; kt < 4; ++kt){
        ar = mfma16(ha[kt], wh[0][kt], ar);
        az = mfma16(ha[kt], wh[1][kt], az);
        an = mfma16(ha[kt], wh[2][kt], an);
      }
      #pragma unroll
      for (int r = 0; r < 4; ++r){
        float rg = sigm(ar[r]);
        float zg = sigm(az[r]);
        float ng = tanh_(gin[r] + rg*(an[r] + bhn_e));
        hreg[r] = ng + zg*(hreg[r] - ng);
      }
      #pragma unroll
      for (int r = 0; r < 4; ++r)
        *(unsigned short*)(hw + (mt*16 + quad*4 + r)*PITCH_H + col*2) = f2bf(hreg[r]);
      __syncthreads();
    }
  }
  // h_enc in hbuf[0]

  // ================= decoder init =================
  f32x4 g0r, g0z, g0n;
  {
    short8 hea[4];
    #pragma unroll
    for (int kt = 0; kt < 4; ++kt)
      hea[kt] = *(const short8*)(smem + O_H + (mt*16 + l15)*PITCH_H + kt*64 + quad*16);
    #pragma unroll
    for (int g = 0; g < 3; ++g){
      short8 bfr[4];
      #pragma unroll
      for (int kt = 0; kt < 4; ++kt) bfr[kt] = ldw(wsw + W_DWIH, g*128 + col, kt, quad);
      f32x4 acc = (f32x4){0.f,0.f,0.f,0.f};
      #pragma unroll
      for (int kt = 0; kt < 4; ++kt) acc = mfma16(hea[kt], bfr[kt], acc);
      if (g == 0) g0r = acc; else if (g == 1) g0z = acc; else g0n = acc;
    }
  }
  // decoder recurrent weights; fc1 frags (wave wv owns fc1 col-tile wv)
  #pragma unroll
  for (int g = 0; g < 3; ++g)
    #pragma unroll
    for (int kt = 0; kt < 4; ++kt)
      wh[g][kt] = ldw(wsw + W_DWHH, g*128 + col, kt, quad);
  short8 f1f[4];
  #pragma unroll
  for (int kt = 0; kt < 4; ++kt)
    f1f[kt] = ldw(wsw + W_FC1, wv*16 + l15, kt, quad);
  __syncthreads();   // encoder-region LDS reads done before FC2D overwrite
  // fc2 -> LDS (repitch 512B rows -> 528B)
  for (int i4 = tid; i4 < 4096; i4 += THREADS){
    int row = i4 >> 6, k8 = i4 & 63;
    *(uint2*)(smem + O_FC2D + row*PITCH_A1 + k8*8) =
        *(const uint2*)(wsw + W_FC2 + row*256 + k8*4);
  }
  // decoder scalar constants
  const float br_d  = dec_bih[col]       + dec_bhh[col];
  const float bz_d  = dec_bih[128 + col] + dec_bhh[128 + col];
  const float bin_d = dec_bih[256 + col];
  const float bhn_d = dec_bhh[256 + col];
  const float fb1   = fc1_b[wv*16 + l15];
  const int   mt2   = (wv >> 2) & 1, nt2 = wv & 3;     // fc2 tile for waves 0..7
  const float fb2   = (wv < 8) ? fc2_b[nt2*16 + l15] : 0.f;
  const int prow = tid / 6, pcol = tid - prow*6;
  float present = 0.f, fb3 = 0.f;
  if (tid < 192){
    present = pbase[(size_t)prow*768 + pcol*128 + 127];
    fb3 = fc3_b[pcol];
  }
  for (int i = tid; i < HBUF/4; i += THREADS) ((unsigned*)(smem + O_H + HBUF))[i] = 0u;
  #pragma unroll
  for (int r = 0; r < 4; ++r) hreg[r] = 0.f;
  __syncthreads();

  // ================= decoder: 30 steps =================
  for (int s = 0; s < 30; ++s){
    const char* hr = smem + O_H + (1 - (s & 1)) * HBUF;
    char*       hw = smem + O_H + (s & 1) * HBUF;
    f32x4 ar, az, gin, an = (f32x4){0.f,0.f,0.f,0.f};
    if (s == 0){
      #pragma unroll
      for (int r = 0; r < 4; ++r){
        ar[r] = g0r[r] + br_d; az[r] = g0z[r] + bz_d; gin[r] = g0n[r] + bin_d;
      }
    } else {
      #pragma unroll
      for (int r = 0; r < 4; ++r){ ar[r] = br_d; az[r] = bz_d; gin[r] = bin_d; }
    }
    {
      short8 ha[4];
      #pragma unroll
      for (int kt = 0; kt < 4; ++kt)
        ha[kt] = *(const short8*)(hr + (mt*16 + l15)*PITCH_H + kt*64 + quad*16);
      #pragma unroll
      for (int kt = 0; kt < 4; ++kt){
        ar = mfma16(ha[kt], wh[0][kt], ar);
        az = mfma16(ha[kt], wh[1][kt], az);
        an = mfma16(ha[kt], wh[2][kt], an);
      }
    }
    #pragma unroll
    for (int r = 0; r < 4; ++r){
      float rg = sigm(ar[r]);
      float zg = sigm(az[r]);
      float ng = tanh_(gin[r] + rg*(an[r] + bhn_d));
      hreg[r] = ng + zg*(hreg[r] - ng);
    }
    #pragma unroll
    for (int r = 0; r < 4; ++r)
      *(unsigned short*)(hw + (mt*16 + quad*4 + r)*PITCH_H + col*2) = f2bf(hreg[r]);
    __syncthreads();   // D1: h(s+1) visible

    // fc1: (32x128)@(128x256) + relu -> a1 ; wave wv: n-tile wv, both m-tiles
    {
      f32x4 a1a[2];
      a1a[0] = (f32x4){0.f,0.f,0.f,0.f}; a1a[1] = a1a[0];
      #pragma unroll
      for (int m2 = 0; m2 < 2; ++m2)
        #pragma unroll
        for (int kt = 0; kt < 4; ++kt){
          short8 hf = *(const short8*)(hw + (m2*16 + l15)*PITCH_H + kt*64 + quad*16);
          a1a[m2] = mfma16(hf, f1f[kt], a1a[m2]);
        }
      #pragma unroll
      for (int m2 = 0; m2 < 2; ++m2)
        #pragma unroll
        for (int r = 0; r < 4; ++r)
          *(unsigned short*)(smem + O_A1D + (m2*16 + quad*4 + r)*PITCH_A1 +
                             (wv*16 + l15)*2) = f2bf(fmaxf(a1a[m2][r] + fb1, 0.f));
    }
    __syncthreads();   // D2: a1 visible

    // fc2: (32x256)@(256x64) -> a2 (waves 0..7)
    if (wv < 8){
      f32x4 a2a = (f32x4){0.f,0.f,0.f,0.f};
      #pragma unroll
      for (int kt = 0; kt < 8; ++kt){
        short8 a = *(const short8*)(smem + O_A1D + (mt2*16 + l15)*PITCH_A1 + kt*64 + quad*16);
        short8 b = *(const short8*)(smem + O_FC2D + (nt2*16 + l15)*PITCH_A1 + kt*64 + quad*16);
        a2a = mfma16(a, b, a2a);
      }
      #pragma unroll
      for (int r = 0; r < 4; ++r)
        *(unsigned short*)(smem + O_A2D + (mt2*16 + quad*4 + r)*144 + (nt2*16 + l15)*2) =
            f2bf(a2a[r] + fb2);
    }
    __syncthreads();   // D3: a2 visible

    // fc3 (6x64, VALU) + present accumulate + store
    if (tid < 192){
      float o = fb3;
      const float* w3 = (const float*)(smem + O_FC3W) + pcol*64;
      #pragma unroll
      for (int kc = 0; kc < 8; ++kc){
        short8 av = *(const short8*)(smem + O_A2D + prow*144 + kc*16);
        #pragma unroll
        for (int j = 0; j < 8; ++j)
          o += bf2f((unsigned short)av[j]) * w3[kc*8 + j];
      }
      present += o;
      out[(size_t)(b0 + prow)*180 + pcol*30 + s] = present;   // (B, 6, 30)
    }
    // a2 reads protected by next step's D1/D2
  }
}

extern "C" void kernel_launch(void* const* d_in, const int* in_sizes, int n_in,
                              void* d_out, int out_size, void* d_ws, size_t ws_size,
                              hipStream_t stream) {
  (void)in_sizes; (void)n_in; (void)out_size; (void)ws_size;
  const float* past     = (const float*)d_in[0];
  const float* conv_w   = (const float*)d_in[1];
  const float* conv_b   = (const float*)d_in[2];
  const float* bn_gamma = (const float*)d_in[3];
  const float* bn_beta  = (const float*)d_in[4];
  const float* bn_mean  = (const float*)d_in[5];
  const float* bn_var   = (const float*)d_in[6];
  const float* enc_wih  = (const float*)d_in[7];
  const float* enc_whh  = (const float*)d_in[8];
  const float* enc_bih  = (const float*)d_in[9];
  const float* enc_bhh  = (const float*)d_in[10];
  const float* dec_wih  = (const float*)d_in[11];
  const float* dec_whh  = (const float*)d_in[12];
  const float* dec_bih  = (const float*)d_in[13];
  const float* dec_bhh  = (const float*)d_in[14];
  const float* fc1_w    = (const float*)d_in[15];
  const float* fc1_b    = (const float*)d_in[16];
  const float* fc2_w    = (const float*)d_in[17];
  const float* fc2_b    = (const float*)d_in[18];
  const float* fc3_w    = (const float*)d_in[19];
  const float* fc3_b    = (const float*)d_in[20];
  unsigned short* wsw   = (unsigned short*)d_ws;

  hipFuncSetAttribute((const void*)gru_fused,
                      hipFuncAttributeMaxDynamicSharedMemorySize, LDS_TOTAL);

  prep_weights<<<256, 256, 0, stream>>>(enc_wih, enc_whh, dec_wih, dec_whh,
                                        fc1_w, fc2_w, wsw);

  gru_fused<<<NBLK, THREADS, LDS_TOTAL, stream>>>(
      past, conv_w, conv_b, bn_gamma, bn_beta, bn_mean, bn_var,
      enc_bih, enc_bhh, dec_bih, dec_bhh,
      fc1_b, fc2_b, fc3_w, fc3_b, wsw,
      (float*)d_out);
}

// Round 8
// 1019.279 us; speedup vs baseline: 1.2326x; 1.0012x over previous
//
#include <hip/hip_runtime.h>

#define DI __device__ __forceinline__

typedef __attribute__((ext_vector_type(8))) short short8;
typedef __attribute__((ext_vector_type(4))) float f32x4;

constexpr int THREADS = 1024;          // 16 waves -> one block fills a CU (4 waves/SIMD)
constexpr int ROWS    = 32;            // batch rows per block
constexpr int NBLK    = 8192 / ROWS;   // 256 blocks = 1 per CU
constexpr int PITCH_H  = 272;          // h rows (K=128 bf16), b128-read conflict-free
constexpr int PITCH_X  = 264;          // x rows, conflict-free
constexpr int PITCH_A1 = 528;          // K=256 bf16 rows

// ---- LDS layout (bytes) ----
constexpr int O_PATCH = 0;        // 10240: 128 rows x 80B (4 steps x 32 rows); conv-w scratch at init
constexpr int O_XALL  = 10240;    // 33792: 128 rows x 264B
constexpr int O_H     = 44032;    // 2 x 8704 hidden double buffer
constexpr int HBUF    = 8704;
constexpr int O_FC3W  = 61440;    // 1536: fc3 weights f32
constexpr int O_A1D   = 62976;    // 16896: a1 (32 x 528)  [decoder]
constexpr int LDS_TOTAL = 79872;
// decoder aliases of [0, 44032):
constexpr int O_FC2D  = 0;        // 33792: 64 x 528
constexpr int O_A2D   = 33792;    // 4608:  32 x 144

// ---- d_ws element offsets (bf16) ----
constexpr int W_EWIH = 0;         // 384x128
constexpr int W_EWHH = 49152;
constexpr int W_DWIH = 98304;
constexpr int W_DWHH = 147456;
constexpr int W_FC1  = 196608;    // 256x128
constexpr int W_FC2  = 229376;    // 64x256

DI unsigned short f2bf(float f){
  union { float f; unsigned u; } v; v.f = f;
  return (unsigned short)((v.u + 0x7fffu + ((v.u >> 16) & 1u)) >> 16);
}
DI float bf2f(unsigned short u){
  union { unsigned u; float f; } v; v.u = ((unsigned)u) << 16;
  return v.f;
}
DI float u2f_lo(unsigned u){ union { unsigned u; float f; } v; v.u = u << 16;        return v.f; }
DI float u2f_hi(unsigned u){ union { unsigned u; float f; } v; v.u = u & 0xffff0000u; return v.f; }
DI float sigm(float x){ return 1.f / (1.f + __expf(-x)); }
DI float tanh_(float x){
  float ax = fabsf(x);
  float e = __expf(-2.f * ax);
  float t = (1.f - e) / (1.f + e);
  return copysignf(t, x);
}
DI f32x4 mfma16(short8 a, short8 b, f32x4 c){
  return __builtin_amdgcn_mfma_f32_16x16x32_bf16(a, b, c, 0, 0, 0);
}
DI uint2 pack4(f32x4 v){
  return make_uint2((unsigned)f2bf(v[0]) | ((unsigned)f2bf(v[1]) << 16),
                    (unsigned)f2bf(v[2]) | ((unsigned)f2bf(v[3]) << 16));
}

// ---------- prep: convert f32 weights -> bf16 in d_ws ----------
__global__ void prep_weights(const float* __restrict__ ewih, const float* __restrict__ ewhh,
                             const float* __restrict__ dwih, const float* __restrict__ dwhh,
                             const float* __restrict__ f1,   const float* __restrict__ f2,
                             unsigned short* __restrict__ ws)
{
  const int gid = blockIdx.x * blockDim.x + threadIdx.x;
  const int stride = gridDim.x * blockDim.x;
  auto cvt = [&](const float* __restrict__ s, unsigned short* __restrict__ d, int n){
    for (int i = gid; i < (n >> 1); i += stride){
      float2 v = ((const float2*)s)[i];
      ((unsigned*)d)[i] = (unsigned)f2bf(v.x) | ((unsigned)f2bf(v.y) << 16);
    }
  };
  cvt(ewih, ws + W_EWIH, 49152);
  cvt(ewhh, ws + W_EWHH, 49152);
  cvt(dwih, ws + W_DWIH, 49152);
  cvt(dwhh, ws + W_DWHH, 49152);
  cvt(f1,   ws + W_FC1,  32768);
  cvt(f2,   ws + W_FC2,  16384);
}

// B-frag load from converted weights: row-major [row][128] bf16
DI short8 ldw(const unsigned short* __restrict__ base, int row, int kt, int quad){
  return *(const short8*)(base + row * 128 + kt * 32 + quad * 8);
}

// __launch_bounds__(1024, 1): the explicit "1" stops the compiler from
// defaulting to a 2-blocks/CU (64-VGPR) target — R7 evidence: (1024) alone
// compiled to VGPR=64 and spilled 2.6 GB/launch. A 1024-thread block already
// hardware-caps VGPRs at 128 (16 waves, 4/SIMD, 512-reg file), which our
// ~118-reg live set fits.
__global__ void __launch_bounds__(THREADS, 1)
gru_fused(const float* __restrict__ past,
          const float* __restrict__ conv_w, const float* __restrict__ conv_b,
          const float* __restrict__ bn_gamma, const float* __restrict__ bn_beta,
          const float* __restrict__ bn_mean, const float* __restrict__ bn_var,
          const float* __restrict__ enc_bih, const float* __restrict__ enc_bhh,
          const float* __restrict__ dec_bih, const float* __restrict__ dec_bhh,
          const float* __restrict__ fc1_b, const float* __restrict__ fc2_b,
          const float* __restrict__ fc3_w, const float* __restrict__ fc3_b,
          const unsigned short* __restrict__ wsw,
          float* __restrict__ out)
{
  extern __shared__ char smem[];
  const int tid  = threadIdx.x;
  const int lane = tid & 63, wv = tid >> 6;       // 16 waves
  const int mt   = wv >> 3, cs = wv & 7;          // m-tile (0/1), col-slice (0..7)
  const int l15  = lane & 15, quad = lane >> 4;
  const int b0   = blockIdx.x * ROWS;
  const int col  = cs * 16 + l15;                 // this thread's gate/h column
  const float* pbase = past + (size_t)b0 * 768;

  // ---- encoder scalar constants ----
  const float br_e  = enc_bih[col]       + enc_bhh[col];
  const float bz_e  = enc_bih[128 + col] + enc_bhh[128 + col];
  const float bin_e = enc_bih[256 + col];
  const float bhn_e = enc_bhh[256 + col];
  const float cb_t  = conv_b[col];
  const float s_bn  = bn_gamma[0] * rsqrtf(bn_var[0] + 1e-5f);
  const float o_bn  = bn_beta[0] - bn_mean[0] * s_bn;

  // ---- recurrent weights -> registers (from d_ws, one-time) ----
  short8 wh[3][4];
  #pragma unroll
  for (int g = 0; g < 3; ++g)
    #pragma unroll
    for (int kt = 0; kt < 4; ++kt)
      wh[g][kt] = ldw(wsw + W_EWHH, g*128 + col, kt, quad);

  // ---- conv weights: cwT[oc][k=c*3+kk] bf16 (80B rows) in PATCH scratch ----
  for (int i = tid; i < 2560; i += THREADS) ((unsigned*)(smem + O_PATCH))[i] = 0u;
  __syncthreads();
  for (int i = tid; i < 2304; i += THREADS){
    int oc = i / 18, kk = i - oc * 18;
    *(unsigned short*)(smem + O_PATCH + oc*80 + kk*2) = f2bf(conv_w[i]);
  }
  __syncthreads();
  const short8 cwf = *(const short8*)(smem + O_PATCH + col*80 + quad*16);

  // ---- zero h double buffer, fc3 weights ----
  for (int i = tid; i < 2*HBUF/4; i += THREADS) ((unsigned*)(smem + O_H))[i] = 0u;
  for (int i = tid; i < 384; i += THREADS) ((float*)(smem + O_FC3W))[i] = fc3_w[i];
  __syncthreads();   // cwf read done before PATCH reused

  float hreg[4] = {0.f, 0.f, 0.f, 0.f};
  uint2 gi_pk[4][3];                    // packed-bf16 gi (bias folded): [tc][gate]

  // ================= encoder: 32 chunks x 4 steps =================
  for (int chunk = 0; chunk < 32; ++chunk){
    const int t0 = chunk * 4;
    // ---- A1: im2col patch, 4 steps x 32 rows x 18, from global (L2-hot) ----
    for (int e = tid; e < 2304; e += THREADS){
      int tc = e / 576, rem = e - tc*576;
      int m = rem / 18, r18 = rem - m*18;
      int c = r18 / 3, kk = r18 - c*3;
      int tin = t0 + tc - 1 + kk;
      float v = (tin >= 0 && tin < 128) ? pbase[(size_t)m*768 + c*128 + tin] : 0.f;
      *(unsigned short*)(smem + O_PATCH + (tc*32 + m)*80 + r18*2) = f2bf(v);
    }
    __syncthreads();
    // ---- A2: conv as M=128 GEMM (4 row-tiles per wave) + bias/relu/bn ----
    #pragma unroll
    for (int i = 0; i < 4; ++i){
      const int rt = mt*4 + i;          // row-tile 0..7
      short8 pa = *(const short8*)(smem + O_PATCH + (rt*16 + l15)*80 + quad*16);
      f32x4 cc = (f32x4){0.f,0.f,0.f,0.f};
      cc = mfma16(pa, cwf, cc);
      #pragma unroll
      for (int r = 0; r < 4; ++r){
        int row = rt*16 + quad*4 + r;
        float vx = s_bn * fmaxf(cc[r] + cb_t, 0.f) + o_bn;
        *(unsigned short*)(smem + O_XALL + row*PITCH_X + col*2) = f2bf(vx);
      }
    }
    __syncthreads();
    // ---- A3: gi GEMM for 4 steps; wf streamed once per gate per chunk ----
    #pragma unroll
    for (int g = 0; g < 3; ++g){
      short8 bfr[4];
      #pragma unroll
      for (int kt = 0; kt < 4; ++kt) bfr[kt] = ldw(wsw + W_EWIH, g*128 + col, kt, quad);
      const float bias = (g == 0) ? br_e : (g == 1) ? bz_e : bin_e;
      #pragma unroll
      for (int tc = 0; tc < 4; ++tc){
        f32x4 acc = (f32x4){0.f,0.f,0.f,0.f};
        #pragma unroll
        for (int kt = 0; kt < 4; ++kt){
          short8 xa = *(const short8*)(smem + O_XALL +
                        (tc*32 + mt*16 + l15)*PITCH_X + kt*64 + quad*16);
          acc = mfma16(xa, bfr[kt], acc);
        }
        #pragma unroll
        for (int r = 0; r < 4; ++r) acc[r] += bias;
        gi_pk[tc][g] = pack4(acc);
      }
    }
    // x_all reads complete before next chunk's A2 (protected by step barriers + A1 barrier)

    // ---- 4 recurrent steps, 1 barrier each ----
    #pragma unroll
    for (int tc = 0; tc < 4; ++tc){
      const int t = t0 + tc;
      const char* hr = smem + O_H + (t & 1) * HBUF;
      char*       hw = smem + O_H + ((t + 1) & 1) * HBUF;
      short8 ha[4];
      #pragma unroll
      for (int kt = 0; kt < 4; ++kt)
        ha[kt] = *(const short8*)(hr + (mt*16 + l15)*PITCH_H + kt*64 + quad*16);
      f32x4 ar, az, gin, an = (f32x4){0.f,0.f,0.f,0.f};
      ar[0]=u2f_lo(gi_pk[tc][0].x); ar[1]=u2f_hi(gi_pk[tc][0].x);
      ar[2]=u2f_lo(gi_pk[tc][0].y); ar[3]=u2f_hi(gi_pk[tc][0].y);
      az[0]=u2f_lo(gi_pk[tc][1].x); az[1]=u2f_hi(gi_pk[tc][1].x);
      az[2]=u2f_lo(gi_pk[tc][1].y); az[3]=u2f_hi(gi_pk[tc][1].y);
      gin[0]=u2f_lo(gi_pk[tc][2].x); gin[1]=u2f_hi(gi_pk[tc][2].x);
      gin[2]=u2f_lo(gi_pk[tc][2].y); gin[3]=u2f_hi(gi_pk[tc][2].y);
      #pragma unroll
      for (int kt = 0; kt < 4; ++kt){
        ar = mfma16(ha[kt], wh[0][kt], ar);
        az = mfma16(ha[kt], wh[1][kt], az);
        an = mfma16(ha[kt], wh[2][kt], an);
      }
      #pragma unroll
      for (int r = 0; r < 4; ++r){
        float rg = sigm(ar[r]);
        float zg = sigm(az[r]);
        float ng = tanh_(gin[r] + rg*(an[r] + bhn_e));
        hreg[r] = ng + zg*(hreg[r] - ng);
      }
      #pragma unroll
      for (int r = 0; r < 4; ++r)
        *(unsigned short*)(hw + (mt*16 + quad*4 + r)*PITCH_H + col*2) = f2bf(hreg[r]);
      __syncthreads();
    }
  }
  // h_enc in hbuf[0]

  // ================= decoder init =================
  f32x4 g0r, g0z, g0n;
  {
    short8 hea[4];
    #pragma unroll
    for (int kt = 0; kt < 4; ++kt)
      hea[kt] = *(const short8*)(smem + O_H + (mt*16 + l15)*PITCH_H + kt*64 + quad*16);
    #pragma unroll
    for (int g = 0; g < 3; ++g){
      short8 bfr[4];
      #pragma unroll
      for (int kt = 0; kt < 4; ++kt) bfr[kt] = ldw(wsw + W_DWIH, g*128 + col, kt, quad);
      f32x4 acc = (f32x4){0.f,0.f,0.f,0.f};
      #pragma unroll
      for (int kt = 0; kt < 4; ++kt) acc = mfma16(hea[kt], bfr[kt], acc);
      if (g == 0) g0r = acc; else if (g == 1) g0z = acc; else g0n = acc;
    }
  }
  // decoder recurrent weights; fc1 frags (wave wv owns fc1 col-tile wv)
  #pragma unroll
  for (int g = 0; g < 3; ++g)
    #pragma unroll
    for (int kt = 0; kt < 4; ++kt)
      wh[g][kt] = ldw(wsw + W_DWHH, g*128 + col, kt, quad);
  short8 f1f[4];
  #pragma unroll
  for (int kt = 0; kt < 4; ++kt)
    f1f[kt] = ldw(wsw + W_FC1, wv*16 + l15, kt, quad);
  __syncthreads();   // encoder-region LDS reads done before FC2D overwrite
  // fc2 -> LDS (repitch 512B rows -> 528B)
  for (int i4 = tid; i4 < 4096; i4 += THREADS){
    int row = i4 >> 6, k8 = i4 & 63;
    *(uint2*)(smem + O_FC2D + row*PITCH_A1 + k8*8) =
        *(const uint2*)(wsw + W_FC2 + row*256 + k8*4);
  }
  // decoder scalar constants
  const float br_d  = dec_bih[col]       + dec_bhh[col];
  const float bz_d  = dec_bih[128 + col] + dec_bhh[128 + col];
  const float bin_d = dec_bih[256 + col];
  const float bhn_d = dec_bhh[256 + col];
  const float fb1   = fc1_b[wv*16 + l15];
  const int   mt2   = (wv >> 2) & 1, nt2 = wv & 3;     // fc2 tile for waves 0..7
  const float fb2   = (wv < 8) ? fc2_b[nt2*16 + l15] : 0.f;
  const int prow = tid / 6, pcol = tid - prow*6;
  float present = 0.f, fb3 = 0.f;
  if (tid < 192){
    present = pbase[(size_t)prow*768 + pcol*128 + 127];
    fb3 = fc3_b[pcol];
  }
  for (int i = tid; i < HBUF/4; i += THREADS) ((unsigned*)(smem + O_H + HBUF))[i] = 0u;
  #pragma unroll
  for (int r = 0; r < 4; ++r) hreg[r] = 0.f;
  __syncthreads();

  // ================= decoder: 30 steps =================
  for (int s = 0; s < 30; ++s){
    const char* hr = smem + O_H + (1 - (s & 1)) * HBUF;
    char*       hw = smem + O_H + (s & 1) * HBUF;
    f32x4 ar, az, gin, an = (f32x4){0.f,0.f,0.f,0.f};
    if (s == 0){
      #pragma unroll
      for (int r = 0; r < 4; ++r){
        ar[r] = g0r[r] + br_d; az[r] = g0z[r] + bz_d; gin[r] = g0n[r] + bin_d;
      }
    } else {
      #pragma unroll
      for (int r = 0; r < 4; ++r){ ar[r] = br_d; az[r] = bz_d; gin[r] = bin_d; }
    }
    {
      short8 ha[4];
      #pragma unroll
      for (int kt = 0; kt < 4; ++kt)
        ha[kt] = *(const short8*)(hr + (mt*16 + l15)*PITCH_H + kt*64 + quad*16);
      #pragma unroll
      for (int kt = 0; kt < 4; ++kt){
        ar = mfma16(ha[kt], wh[0][kt], ar);
        az = mfma16(ha[kt], wh[1][kt], az);
        an = mfma16(ha[kt], wh[2][kt], an);
      }
    }
    #pragma unroll
    for (int r = 0; r < 4; ++r){
      float rg = sigm(ar[r]);
      float zg = sigm(az[r]);
      float ng = tanh_(gin[r] + rg*(an[r] + bhn_d));
      hreg[r] = ng + zg*(hreg[r] - ng);
    }
    #pragma unroll
    for (int r = 0; r < 4; ++r)
      *(unsigned short*)(hw + (mt*16 + quad*4 + r)*PITCH_H + col*2) = f2bf(hreg[r]);
    __syncthreads();   // D1: h(s+1) visible

    // fc1: (32x128)@(128x256) + relu -> a1 ; wave wv: n-tile wv, both m-tiles
    {
      f32x4 a1a[2];
      a1a[0] = (f32x4){0.f,0.f,0.f,0.f}; a1a[1] = a1a[0];
      #pragma unroll
      for (int m2 = 0; m2 < 2; ++m2)
        #pragma unroll
        for (int kt = 0; kt < 4; ++kt){
          short8 hf = *(const short8*)(hw + (m2*16 + l15)*PITCH_H + kt*64 + quad*16);
          a1a[m2] = mfma16(hf, f1f[kt], a1a[m2]);
        }
      #pragma unroll
      for (int m2 = 0; m2 < 2; ++m2)
        #pragma unroll
        for (int r = 0; r < 4; ++r)
          *(unsigned short*)(smem + O_A1D + (m2*16 + quad*4 + r)*PITCH_A1 +
                             (wv*16 + l15)*2) = f2bf(fmaxf(a1a[m2][r] + fb1, 0.f));
    }
    __syncthreads();   // D2: a1 visible

    // fc2: (32x256)@(256x64) -> a2 (waves 0..7)
    if (wv < 8){
      f32x4 a2a = (f32x4){0.f,0.f,0.f,0.f};
      #pragma unroll
      for (int kt = 0; kt < 8; ++kt){
        short8 a = *(const short8*)(smem + O_A1D + (mt2*16 + l15)*PITCH_A1 + kt*64 + quad*16);
        short8 b = *(const short8*)(smem + O_FC2D + (nt2*16 + l15)*PITCH_A1 + kt*64 + quad*16);
        a2a = mfma16(a, b, a2a);
      }
      #pragma unroll
      for (int r = 0; r < 4; ++r)
        *(unsigned short*)(smem + O_A2D + (mt2*16 + quad*4 + r)*144 + (nt2*16 + l15)*2) =
            f2bf(a2a[r] + fb2);
    }
    __syncthreads();   // D3: a2 visible

    // fc3 (6x64, VALU) + present accumulate + store
    if (tid < 192){
      float o = fb3;
      const float* w3 = (const float*)(smem + O_FC3W) + pcol*64;
      #pragma unroll
      for (int kc = 0; kc < 8; ++kc){
        short8 av = *(const short8*)(smem + O_A2D + prow*144 + kc*16);
        #pragma unroll
        for (int j = 0; j < 8; ++j)
          o += bf2f((unsigned short)av[j]) * w3[kc*8 + j];
      }
      present += o;
      out[(size_t)(b0 + prow)*180 + pcol*30 + s] = present;   // (B, 6, 30)
    }
    // a2 reads protected by next step's D1/D2
  }
}

extern "C" void kernel_launch(void* const* d_in, const int* in_sizes, int n_in,
                              void* d_out, int out_size, void* d_ws, size_t ws_size,
                              hipStream_t stream) {
  (void)in_sizes; (void)n_in; (void)out_size; (void)ws_size;
  const float* past     = (const float*)d_in[0];
  const float* conv_w   = (const float*)d_in[1];
  const float* conv_b   = (const float*)d_in[2];
  const float* bn_gamma = (const float*)d_in[3];
  const float* bn_beta  = (const float*)d_in[4];
  const float* bn_mean  = (const float*)d_in[5];
  const float* bn_var   = (const float*)d_in[6];
  const float* enc_wih  = (const float*)d_in[7];
  const float* enc_whh  = (const float*)d_in[8];
  const float* enc_bih  = (const float*)d_in[9];
  const float* enc_bhh  = (const float*)d_in[10];
  const float* dec_wih  = (const float*)d_in[11];
  const float* dec_whh  = (const float*)d_in[12];
  const float* dec_bih  = (const float*)d_in[13];
  const float* dec_bhh  = (const float*)d_in[14];
  const float* fc1_w    = (const float*)d_in[15];
  const float* fc1_b    = (const float*)d_in[16];
  const float* fc2_w    = (const float*)d_in[17];
  const float* fc2_b    = (const float*)d_in[18];
  const float* fc3_w    = (const float*)d_in[19];
  const float* fc3_b    = (const float*)d_in[20];
  unsigned short* wsw   = (unsigned short*)d_ws;

  hipFuncSetAttribute((const void*)gru_fused,
                      hipFuncAttributeMaxDynamicSharedMemorySize, LDS_TOTAL);

  prep_weights<<<256, 256, 0, stream>>>(enc_wih, enc_whh, dec_wih, dec_whh,
                                        fc1_w, fc2_w, wsw);

  gru_fused<<<NBLK, THREADS, LDS_TOTAL, stream>>>(
      past, conv_w, conv_b, bn_gamma, bn_beta, bn_mean, bn_var,
      enc_bih, enc_bhh, dec_bih, dec_bhh,
      fc1_b, fc2_b, fc3_w, fc3_b, wsw,
      (float*)d_out);
}